// Round 1
// baseline (1547.962 us; speedup 1.0000x reference)
//
#include <hip/hip_runtime.h>
#include <hip/hip_bf16.h>

// SpatialTransformer block on MI355X. Round 0: correctness-first full pipeline.
// bf16 MFMA GEMMs (fp32 accum), fp32 flash attention, fused epilogues
// (bias/residual/gelu-gate), all intermediates in d_ws.

#define HD 8       // heads
#define DHD 80     // head dim
#define CCH 640    // channels
#define SQ 1024    // spatial tokens per batch
#define NB 8       // batch

using short8  = __attribute__((ext_vector_type(8))) short;
using floatx4 = __attribute__((ext_vector_type(4))) float;

__device__ __forceinline__ float bf2f(ushort u) {
  union { unsigned int i; float f; } v; v.i = ((unsigned int)u) << 16; return v.f;
}
__device__ __forceinline__ ushort f2bf(float f) {
  union { float f; unsigned int i; } v; v.f = f;
  unsigned int r = v.i + 0x7FFFu + ((v.i >> 16) & 1u);
  return (ushort)(r >> 16);
}

// ---------------------------------------------------------------- GEMM
// C[M,N] = A[M,K](bf16) @ BT[N,K](bf16)^T  (+bias) (*gelu(aux)) (+res) -> outF/outB
// 128x128 tile, BK=32, 4 waves in 2x2, each wave 64x64 via 4x4 mfma 16x16x32.
#define LSTR 40   // LDS row stride (bf16): 32 + 8 pad -> 2-way-max bank aliasing

__global__ __launch_bounds__(256) void gemm_bf16_kernel(
    const ushort* __restrict__ A, const ushort* __restrict__ BT,
    const float* __restrict__ bias, const float* __restrict__ res,
    const ushort* __restrict__ aux, float* __restrict__ outF,
    ushort* __restrict__ outB, int M, int N, int K)
{
  __shared__ ushort As[128][LSTR];
  __shared__ ushort Bs[128][LSTR];
  const int tid  = threadIdx.x;
  const int lane = tid & 63;
  const int wave = tid >> 6;
  const int wm = (wave >> 1) * 64;
  const int wn = (wave & 1) * 64;
  const int bm = blockIdx.x * 128;
  const int bn = blockIdx.y * 128;
  const int fr = lane & 15;          // fragment row/col
  const int fk = (lane >> 4) * 8;    // k offset within BK=32

  floatx4 acc[4][4];
  #pragma unroll
  for (int i = 0; i < 4; ++i)
    #pragma unroll
    for (int j = 0; j < 4; ++j)
      acc[i][j] = (floatx4){0.f, 0.f, 0.f, 0.f};

  const int r0 = tid >> 2;           // 0..63
  const int c0 = (tid & 3) * 8;      // 0,8,16,24

  for (int kt = 0; kt < K; kt += 32) {
    #pragma unroll
    for (int it = 0; it < 2; ++it) {
      int r  = r0 + it * 64;
      int gm = bm + r;
      uint4 va = make_uint4(0u, 0u, 0u, 0u);
      if (gm < M) va = *(const uint4*)(A + (size_t)gm * K + kt + c0);
      *(uint4*)(&As[r][c0]) = va;
      int gn = bn + r;
      uint4 vb = make_uint4(0u, 0u, 0u, 0u);
      if (gn < N) vb = *(const uint4*)(BT + (size_t)gn * K + kt + c0);
      *(uint4*)(&Bs[r][c0]) = vb;
    }
    __syncthreads();
    short8 af[4], bfr[4];
    #pragma unroll
    for (int mi = 0; mi < 4; ++mi)
      af[mi] = *(const short8*)(&As[wm + mi * 16 + fr][fk]);
    #pragma unroll
    for (int ni = 0; ni < 4; ++ni)
      bfr[ni] = *(const short8*)(&Bs[wn + ni * 16 + fr][fk]);
    #pragma unroll
    for (int mi = 0; mi < 4; ++mi)
      #pragma unroll
      for (int ni = 0; ni < 4; ++ni)
        acc[mi][ni] = __builtin_amdgcn_mfma_f32_16x16x32_bf16(
            af[mi], bfr[ni], acc[mi][ni], 0, 0, 0);
    __syncthreads();
  }

  const int fq = (lane >> 4) * 4;
  #pragma unroll
  for (int mi = 0; mi < 4; ++mi) {
    #pragma unroll
    for (int rr = 0; rr < 4; ++rr) {
      int gm = bm + wm + mi * 16 + fq + rr;
      if (gm >= M) continue;
      #pragma unroll
      for (int ni = 0; ni < 4; ++ni) {
        int col = bn + wn + ni * 16 + fr;
        float v = acc[mi][ni][rr];
        if (bias) v += bias[col];
        if (aux) {  // GEGLU: v(=xx+bias) * gelu_tanh(gate)
          float g = bf2f(aux[(size_t)gm * N + col]);
          float t = tanhf(0.7978845608f * g * (1.0f + 0.044715f * g * g));
          v = v * 0.5f * g * (1.0f + t);
        }
        if (res) v += res[(size_t)gm * N + col];
        size_t o = (size_t)gm * N + col;
        if (outF) outF[o] = v;
        if (outB) outB[o] = f2bf(v);
      }
    }
  }
}

// ---------------------------------------------------------------- attention
// fp32 flash attention; thread (r,j): 4 q-rows (r, r+32, r+64, r+96), dims j+8*dd.
// K/V staged dim-major [80][20] (pad->conflict-free b128 reads, broadcast over r).
#define KTILE 16

__global__ __launch_bounds__(256) void attn_kernel(
    const ushort* __restrict__ Q, const ushort* __restrict__ Kb,
    const ushort* __restrict__ Vb, ushort* __restrict__ O,
    int Sq, int Sk)
{
  __shared__ float KsT[DHD][20];
  __shared__ float VsT[DHD][20];
  const int tid = threadIdx.x;
  const int rT  = tid >> 3;       // 0..31
  const int j   = tid & 7;        // 0..7
  const int nqt = Sq >> 7;        // q-tiles of 128 rows
  const int qt  = blockIdx.x % nqt;
  const int bh  = blockIdx.x / nqt;
  const int h   = bh % HD;
  const int b   = bh / HD;
  const int qbase = qt * 128 + rT;

  const float scale = 0.11180339887498949f;  // 80^-0.5
  float q[4][10], o[4][10];
  #pragma unroll
  for (int rr = 0; rr < 4; ++rr) {
    size_t qrow = (size_t)(b * Sq + qbase + rr * 32);
    #pragma unroll
    for (int dd = 0; dd < 10; ++dd) {
      q[rr][dd] = bf2f(Q[qrow * CCH + h * DHD + j + dd * 8]) * scale;
      o[rr][dd] = 0.f;
    }
  }
  float m[4] = {-1e30f, -1e30f, -1e30f, -1e30f};
  float l[4] = {0.f, 0.f, 0.f, 0.f};

  for (int kt = 0; kt < Sk; kt += KTILE) {
    __syncthreads();
    for (int i = tid; i < DHD * KTILE; i += 256) {
      int kr = i / DHD, kc = i % DHD;
      int gk = kt + kr;
      float kv = 0.f, vv = 0.f;
      if (gk < Sk) {
        size_t off = (size_t)(b * Sk + gk) * CCH + h * DHD + kc;
        kv = bf2f(Kb[off]);
        vv = bf2f(Vb[off]);
      }
      KsT[kc][kr] = kv;
      VsT[kc][kr] = vv;
    }
    __syncthreads();

    float s[4][KTILE];
    #pragma unroll
    for (int rr = 0; rr < 4; ++rr)
      #pragma unroll
      for (int kk = 0; kk < KTILE; ++kk) s[rr][kk] = 0.f;

    #pragma unroll
    for (int dd = 0; dd < 10; ++dd) {
      int d = j + dd * 8;
      float kvv[KTILE];
      #pragma unroll
      for (int k4 = 0; k4 < KTILE / 4; ++k4) {
        float4 t = *(const float4*)(&KsT[d][k4 * 4]);
        kvv[k4*4+0] = t.x; kvv[k4*4+1] = t.y; kvv[k4*4+2] = t.z; kvv[k4*4+3] = t.w;
      }
      #pragma unroll
      for (int rr = 0; rr < 4; ++rr)
        #pragma unroll
        for (int kk = 0; kk < KTILE; ++kk)
          s[rr][kk] += q[rr][dd] * kvv[kk];
    }
    // reduce partial dots across the 8 j-lanes (consecutive lanes in wave)
    #pragma unroll
    for (int rr = 0; rr < 4; ++rr)
      #pragma unroll
      for (int kk = 0; kk < KTILE; ++kk) {
        float v = s[rr][kk];
        v += __shfl_xor(v, 1);
        v += __shfl_xor(v, 2);
        v += __shfl_xor(v, 4);
        s[rr][kk] = (kt + kk < Sk) ? v : -1e30f;
      }
    #pragma unroll
    for (int rr = 0; rr < 4; ++rr) {
      float cm = s[rr][0];
      #pragma unroll
      for (int kk = 1; kk < KTILE; ++kk) cm = fmaxf(cm, s[rr][kk]);
      float mn = fmaxf(m[rr], cm);
      float al = __expf(m[rr] - mn);
      m[rr] = mn;
      l[rr] *= al;
      #pragma unroll
      for (int dd = 0; dd < 10; ++dd) o[rr][dd] *= al;
      #pragma unroll
      for (int kk = 0; kk < KTILE; ++kk) {
        float p = __expf(s[rr][kk] - mn);
        s[rr][kk] = p;
        l[rr] += p;
      }
    }
    #pragma unroll
    for (int dd = 0; dd < 10; ++dd) {
      int d = j + dd * 8;
      float vvv[KTILE];
      #pragma unroll
      for (int k4 = 0; k4 < KTILE / 4; ++k4) {
        float4 t = *(const float4*)(&VsT[d][k4 * 4]);
        vvv[k4*4+0] = t.x; vvv[k4*4+1] = t.y; vvv[k4*4+2] = t.z; vvv[k4*4+3] = t.w;
      }
      #pragma unroll
      for (int rr = 0; rr < 4; ++rr)
        #pragma unroll
        for (int kk = 0; kk < KTILE; ++kk)
          o[rr][dd] += s[rr][kk] * vvv[kk];
    }
  }
  #pragma unroll
  for (int rr = 0; rr < 4; ++rr) {
    float inv = 1.f / l[rr];
    size_t qrow = (size_t)(b * Sq + qbase + rr * 32);
    #pragma unroll
    for (int dd = 0; dd < 10; ++dd)
      O[qrow * CCH + h * DHD + j + dd * 8] = f2bf(o[rr][dd] * inv);
  }
}

// ---------------------------------------------------------------- norms
__global__ __launch_bounds__(256) void layernorm_kernel(
    const float* __restrict__ X, const float* __restrict__ g,
    const float* __restrict__ bt, ushort* __restrict__ out)
{
  int row  = blockIdx.x * 4 + (threadIdx.x >> 6);
  int lane = threadIdx.x & 63;
  const float* xr = X + (size_t)row * CCH;
  float v[10];
  float s = 0.f, ss = 0.f;
  #pragma unroll
  for (int i = 0; i < 10; ++i) {
    float x = xr[lane + i * 64];
    v[i] = x; s += x; ss += x * x;
  }
  #pragma unroll
  for (int msk = 1; msk < 64; msk <<= 1) {
    s += __shfl_xor(s, msk);
    ss += __shfl_xor(ss, msk);
  }
  float mean = s * (1.f / 640.f);
  float var  = ss * (1.f / 640.f) - mean * mean;
  float rs   = rsqrtf(var + 1e-5f);
  ushort* orow = out + (size_t)row * CCH;
  #pragma unroll
  for (int i = 0; i < 10; ++i) {
    int c = lane + i * 64;
    orow[c] = f2bf((v[i] - mean) * rs * g[c] + bt[c]);
  }
}

__global__ __launch_bounds__(256) void groupnorm_kernel(
    const float* __restrict__ X, const float* __restrict__ gamma,
    const float* __restrict__ beta, ushort* __restrict__ out)
{
  int b = blockIdx.x >> 5;
  int g = blockIdx.x & 31;
  int tid = threadIdx.x;
  const float* base = X + (size_t)b * SQ * CCH + g * 20;
  float s = 0.f, ss = 0.f;
  for (int p = tid; p < SQ; p += 256) {
    const float* rp = base + (size_t)p * CCH;
    #pragma unroll
    for (int c = 0; c < 20; ++c) { float x = rp[c]; s += x; ss += x * x; }
  }
  #pragma unroll
  for (int msk = 1; msk < 64; msk <<= 1) { s += __shfl_xor(s, msk); ss += __shfl_xor(ss, msk); }
  __shared__ float red[2][4];
  int lane = tid & 63, wv = tid >> 6;
  if (lane == 0) { red[0][wv] = s; red[1][wv] = ss; }
  __syncthreads();
  s  = red[0][0] + red[0][1] + red[0][2] + red[0][3];
  ss = red[1][0] + red[1][1] + red[1][2] + red[1][3];
  float mean = s * (1.f / 20480.f);
  float var  = ss * (1.f / 20480.f) - mean * mean;
  float rstd = rsqrtf(var + 1e-5f);
  ushort* ob = out + (size_t)b * SQ * CCH + g * 20;
  for (int p = tid; p < SQ; p += 256) {
    const float* rp = base + (size_t)p * CCH;
    ushort* op = ob + (size_t)p * CCH;
    #pragma unroll
    for (int c = 0; c < 20; ++c)
      op[c] = f2bf((rp[c] - mean) * rstd * gamma[g * 20 + c] + beta[g * 20 + c]);
  }
}

// ---------------------------------------------------------------- prep
// WT[n*K + k] = bf16(W[k*ld + coff + n])
__global__ void transpose_cast_kernel(const float* __restrict__ W, ushort* __restrict__ WT,
                                      int K, int ld, int coff)
{
  int k = blockIdx.x * 256 + threadIdx.x;
  int n = blockIdx.y;
  if (k < K) WT[(size_t)n * K + k] = f2bf(W[(size_t)k * ld + coff + n]);
}

__global__ void cast_kernel(const float* __restrict__ X, ushort* __restrict__ Y, int n)
{
  int i = blockIdx.x * 256 + threadIdx.x;
  if (i < n) Y[i] = f2bf(X[i]);
}

// ---------------------------------------------------------------- host
static inline void gemm(hipStream_t st, const ushort* A, const ushort* BT,
                        const float* bias, const float* res, const ushort* aux,
                        float* outF, ushort* outB, int M, int N, int K)
{
  dim3 g((M + 127) / 128, N / 128);
  gemm_bf16_kernel<<<g, dim3(256), 0, st>>>(A, BT, bias, res, aux, outF, outB, M, N, K);
}

extern "C" void kernel_launch(void* const* d_in, const int* in_sizes, int n_in,
                              void* d_out, int out_size, void* d_ws, size_t ws_size,
                              hipStream_t stream)
{
  const float* inputs  = (const float*)d_in[0];
  const float* context = (const float*)d_in[1];
  const float* gn_g    = (const float*)d_in[2];
  const float* gn_b    = (const float*)d_in[3];
  const float* w_proj1 = (const float*)d_in[4];
  const float* b_proj1 = (const float*)d_in[5];
  const float* ln1_g   = (const float*)d_in[6];
  const float* ln1_b   = (const float*)d_in[7];
  const float* wq1     = (const float*)d_in[8];
  const float* wk1     = (const float*)d_in[9];
  const float* wv1     = (const float*)d_in[10];
  const float* wo1     = (const float*)d_in[11];
  const float* bo1     = (const float*)d_in[12];
  const float* ln2_g   = (const float*)d_in[13];
  const float* ln2_b   = (const float*)d_in[14];
  const float* wq2     = (const float*)d_in[15];
  const float* wk2     = (const float*)d_in[16];
  const float* wv2     = (const float*)d_in[17];
  const float* wo2     = (const float*)d_in[18];
  const float* bo2     = (const float*)d_in[19];
  const float* ln3_g   = (const float*)d_in[20];
  const float* ln3_b   = (const float*)d_in[21];
  const float* w_geglu = (const float*)d_in[22];
  const float* b_geglu = (const float*)d_in[23];
  const float* w_ffout = (const float*)d_in[24];
  const float* b_ffout = (const float*)d_in[25];
  const float* w_proj2 = (const float*)d_in[26];
  const float* b_proj2 = (const float*)d_in[27];

  char* p = (char*)d_ws;
  auto alloc = [&](size_t bytes) -> char* {
    char* r = p; p += (bytes + 255) & ~(size_t)255; return r;
  };
  ushort* wT_p1 = (ushort*)alloc(640 * 640 * 2);
  ushort* wT_q1 = (ushort*)alloc(640 * 640 * 2);
  ushort* wT_k1 = (ushort*)alloc(640 * 640 * 2);
  ushort* wT_v1 = (ushort*)alloc(640 * 640 * 2);
  ushort* wT_o1 = (ushort*)alloc(640 * 640 * 2);
  ushort* wT_q2 = (ushort*)alloc(640 * 640 * 2);
  ushort* wT_k2 = (ushort*)alloc(640 * 768 * 2);
  ushort* wT_v2 = (ushort*)alloc(640 * 768 * 2);
  ushort* wT_o2 = (ushort*)alloc(640 * 640 * 2);
  ushort* wT_gx = (ushort*)alloc(2560 * 640 * 2);
  ushort* wT_gg = (ushort*)alloc(2560 * 640 * 2);
  ushort* wT_ff = (ushort*)alloc(640 * 2560 * 2);
  ushort* wT_p2 = (ushort*)alloc(640 * 640 * 2);
  ushort* ctxb  = (ushort*)alloc(616 * 768 * 2);
  float*  x     = (float*)alloc((size_t)8192 * 640 * 4);
  ushort* lnb   = (ushort*)alloc((size_t)8192 * 640 * 2);
  ushort* qb    = (ushort*)alloc((size_t)8192 * 640 * 2);
  ushort* kb    = (ushort*)alloc((size_t)8192 * 640 * 2);
  ushort* vb    = (ushort*)alloc((size_t)8192 * 640 * 2);
  ushort* ab    = (ushort*)alloc((size_t)8192 * 640 * 2);
  ushort* gateb = qb;  // alias: q/k/v/ab dead before GEGLU (4*10.25MB = 8192*2560*2)
  ushort* hb    = (ushort*)alloc((size_t)8192 * 2560 * 2);

  auto T = [&](const float* W, ushort* WT, int K, int Nout, int ld, int coff) {
    dim3 g((K + 255) / 256, Nout);
    transpose_cast_kernel<<<g, dim3(256), 0, stream>>>(W, WT, K, ld, coff);
  };
  // weight prep (bf16, transposed to N x K)
  T(w_proj1, wT_p1, 640, 640, 640, 0);
  T(wq1, wT_q1, 640, 640, 640, 0);
  T(wk1, wT_k1, 640, 640, 640, 0);
  T(wv1, wT_v1, 640, 640, 640, 0);
  T(wo1, wT_o1, 640, 640, 640, 0);
  T(wq2, wT_q2, 640, 640, 640, 0);
  T(wk2, wT_k2, 768, 640, 640, 0);
  T(wv2, wT_v2, 768, 640, 640, 0);
  T(wo2, wT_o2, 640, 640, 640, 0);
  T(w_geglu, wT_gx, 640, 2560, 5120, 0);
  T(w_geglu, wT_gg, 640, 2560, 5120, 2560);
  T(w_ffout, wT_ff, 2560, 640, 640, 0);
  T(w_proj2, wT_p2, 640, 640, 640, 0);
  cast_kernel<<<dim3((616 * 768 + 255) / 256), dim3(256), 0, stream>>>(context, ctxb, 616 * 768);

  // GN -> proj1 -> x
  groupnorm_kernel<<<dim3(256), dim3(256), 0, stream>>>(inputs, gn_g, gn_b, lnb);
  gemm(stream, lnb, wT_p1, b_proj1, nullptr, nullptr, x, nullptr, 8192, 640, 640);

  // self-attention
  layernorm_kernel<<<dim3(2048), dim3(256), 0, stream>>>(x, ln1_g, ln1_b, lnb);
  gemm(stream, lnb, wT_q1, nullptr, nullptr, nullptr, nullptr, qb, 8192, 640, 640);
  gemm(stream, lnb, wT_k1, nullptr, nullptr, nullptr, nullptr, kb, 8192, 640, 640);
  gemm(stream, lnb, wT_v1, nullptr, nullptr, nullptr, nullptr, vb, 8192, 640, 640);
  attn_kernel<<<dim3(512), dim3(256), 0, stream>>>(qb, kb, vb, ab, 1024, 1024);
  gemm(stream, ab, wT_o1, bo1, x, nullptr, x, nullptr, 8192, 640, 640);

  // cross-attention
  layernorm_kernel<<<dim3(2048), dim3(256), 0, stream>>>(x, ln2_g, ln2_b, lnb);
  gemm(stream, lnb, wT_q2, nullptr, nullptr, nullptr, nullptr, qb, 8192, 640, 640);
  gemm(stream, ctxb, wT_k2, nullptr, nullptr, nullptr, nullptr, kb, 616, 640, 768);
  gemm(stream, ctxb, wT_v2, nullptr, nullptr, nullptr, nullptr, vb, 616, 640, 768);
  attn_kernel<<<dim3(512), dim3(256), 0, stream>>>(qb, kb, vb, ab, 1024, 77);
  gemm(stream, ab, wT_o2, bo2, x, nullptr, x, nullptr, 8192, 640, 640);

  // GEGLU FF
  layernorm_kernel<<<dim3(2048), dim3(256), 0, stream>>>(x, ln3_g, ln3_b, lnb);
  gemm(stream, lnb, wT_gg, b_geglu + 2560, nullptr, nullptr, nullptr, gateb, 8192, 2560, 640);
  gemm(stream, lnb, wT_gx, b_geglu, nullptr, gateb, nullptr, hb, 8192, 2560, 640);
  gemm(stream, hb, wT_ff, b_ffout, x, nullptr, x, nullptr, 8192, 640, 2560);

  // proj2 + input residual -> out
  cast_kernel<<<dim3((8192 * 640 + 255) / 256), dim3(256), 0, stream>>>(x, lnb, 8192 * 640);
  gemm(stream, lnb, wT_p2, b_proj2, inputs, nullptr, (float*)d_out, nullptr, 8192, 640, 640);
}

// Round 2
// 790.732 us; speedup vs baseline: 1.9576x; 1.9576x over previous
//
#include <hip/hip_runtime.h>
#include <hip/hip_bf16.h>

// SpatialTransformer on MI355X. Round 1: MFMA flash attention + global_load_lds
// GEMM staging + merged QKV / dual-B GEGLU GEMM.

#define HD 8
#define DHD 80
#define CCH 640
#define SQ 1024

using short8  = __attribute__((ext_vector_type(8))) short;
using floatx4 = __attribute__((ext_vector_type(4))) float;

__device__ __forceinline__ float bf2f(ushort u) {
  union { unsigned int i; float f; } v; v.i = ((unsigned int)u) << 16; return v.f;
}
__device__ __forceinline__ ushort f2bf(float f) {
  union { float f; unsigned int i; } v; v.f = f;
  unsigned int r = v.i + 0x7FFFu + ((v.i >> 16) & 1u);
  return (ushort)(r >> 16);
}

typedef const __attribute__((address_space(1))) void* gas_ptr;
typedef __attribute__((address_space(3))) void* las_ptr;
__device__ __forceinline__ void gload_lds16(const void* g, void* l) {
  __builtin_amdgcn_global_load_lds((gas_ptr)g, (las_ptr)l, 16, 0, 0);
}

// ---------------------------------------------------------------- GEMM
// C[M,N] = A[M,K]@BT[N,K]^T (+bias)(+res) -> outF/outB. 128x128 tile, BK=32,
// 4 waves 2x2, wave 64x64 = 4x4 mfma 16x16x32. Staging: global_load_lds w=16
// (LDS [128][32] linear, dest = wave base + lane*16). Tail blocks (M%128)
// use predicated vector-load path.
__global__ __launch_bounds__(256) void gemm_bf16_kernel(
    const ushort* __restrict__ A, const ushort* __restrict__ BT,
    const float* __restrict__ bias, const float* __restrict__ res,
    float* __restrict__ outF, ushort* __restrict__ outB, int M, int N, int K)
{
  __shared__ ushort As[128][32];
  __shared__ ushort Bs[128][32];
  const int tid  = threadIdx.x;
  const int lane = tid & 63;
  const int wave = tid >> 6;
  const int wm = (wave >> 1) * 64, wn = (wave & 1) * 64;
  const int bm = blockIdx.x * 128, bn = blockIdx.y * 128;
  const int fr = lane & 15, fk = (lane >> 4) * 8;
  const bool full = (bm + 128 <= M);

  floatx4 acc[4][4];
  #pragma unroll
  for (int i = 0; i < 4; ++i)
    #pragma unroll
    for (int j = 0; j < 4; ++j) acc[i][j] = (floatx4){0.f, 0.f, 0.f, 0.f};

  const int r0 = tid >> 2, c0 = (tid & 3) * 8;        // tail path
  const int lr = lane >> 2, lc = (lane & 3) * 8;      // fast path (per-lane)

  for (int kt = 0; kt < K; kt += 32) {
    if (full) {
      #pragma unroll
      for (int it = 0; it < 2; ++it) {
        const int rb = wave * 16 + it * 64;
        gload_lds16(A  + (size_t)(bm + rb + lr) * K + kt + lc, &As[rb][0]);
        gload_lds16(BT + (size_t)(bn + rb + lr) * K + kt + lc, &Bs[rb][0]);
      }
    } else {
      #pragma unroll
      for (int it = 0; it < 2; ++it) {
        int r = r0 + it * 64;
        int gm = bm + r;
        uint4 va = make_uint4(0u, 0u, 0u, 0u);
        if (gm < M) va = *(const uint4*)(A + (size_t)gm * K + kt + c0);
        *(uint4*)(&As[r][c0]) = va;
        int gn = bn + r;
        uint4 vb = make_uint4(0u, 0u, 0u, 0u);
        if (gn < N) vb = *(const uint4*)(BT + (size_t)gn * K + kt + c0);
        *(uint4*)(&Bs[r][c0]) = vb;
      }
    }
    __syncthreads();
    short8 af[4], bfr[4];
    #pragma unroll
    for (int mi = 0; mi < 4; ++mi) af[mi]  = *(const short8*)(&As[wm + mi * 16 + fr][fk]);
    #pragma unroll
    for (int ni = 0; ni < 4; ++ni) bfr[ni] = *(const short8*)(&Bs[wn + ni * 16 + fr][fk]);
    #pragma unroll
    for (int mi = 0; mi < 4; ++mi)
      #pragma unroll
      for (int ni = 0; ni < 4; ++ni)
        acc[mi][ni] = __builtin_amdgcn_mfma_f32_16x16x32_bf16(af[mi], bfr[ni], acc[mi][ni], 0, 0, 0);
    __syncthreads();
  }

  const int fq = (lane >> 4) * 4;
  #pragma unroll
  for (int mi = 0; mi < 4; ++mi)
    #pragma unroll
    for (int rr = 0; rr < 4; ++rr) {
      int gm = bm + wm + mi * 16 + fq + rr;
      if (gm >= M) continue;
      #pragma unroll
      for (int ni = 0; ni < 4; ++ni) {
        int col = bn + wn + ni * 16 + fr;
        float v = acc[mi][ni][rr];
        if (bias) v += bias[col];
        if (res) v += res[(size_t)gm * N + col];
        size_t o = (size_t)gm * N + col;
        if (outF) outF[o] = v;
        if (outB) outB[o] = f2bf(v);
      }
    }
}

// Dual-B GEGLU GEMM: out[gm,col] = (A@Bx + bx)[gm,col] * gelu((A@Bg + bg)[gm,col])
__global__ __launch_bounds__(256) void gemm_geglu_kernel(
    const ushort* __restrict__ A, const ushort* __restrict__ BTx,
    const ushort* __restrict__ BTg, const float* __restrict__ bx,
    const float* __restrict__ bg, ushort* __restrict__ outB, int M, int N, int K)
{
  __shared__ ushort As[128][32];
  __shared__ ushort Bsx[128][32];
  __shared__ ushort Bsg[128][32];
  const int tid  = threadIdx.x;
  const int lane = tid & 63;
  const int wave = tid >> 6;
  const int wm = (wave >> 1) * 64, wn = (wave & 1) * 64;
  const int bm = blockIdx.x * 128, bn = blockIdx.y * 128;
  const int fr = lane & 15, fk = (lane >> 4) * 8;
  const int lr = lane >> 2, lc = (lane & 3) * 8;

  floatx4 accx[4][4], accg[4][4];
  #pragma unroll
  for (int i = 0; i < 4; ++i)
    #pragma unroll
    for (int j = 0; j < 4; ++j) {
      accx[i][j] = (floatx4){0.f, 0.f, 0.f, 0.f};
      accg[i][j] = (floatx4){0.f, 0.f, 0.f, 0.f};
    }

  for (int kt = 0; kt < K; kt += 32) {
    #pragma unroll
    for (int it = 0; it < 2; ++it) {
      const int rb = wave * 16 + it * 64;
      gload_lds16(A   + (size_t)(bm + rb + lr) * K + kt + lc, &As[rb][0]);
      gload_lds16(BTx + (size_t)(bn + rb + lr) * K + kt + lc, &Bsx[rb][0]);
      gload_lds16(BTg + (size_t)(bn + rb + lr) * K + kt + lc, &Bsg[rb][0]);
    }
    __syncthreads();
    short8 af[4], bfx[4], bfg[4];
    #pragma unroll
    for (int mi = 0; mi < 4; ++mi) af[mi]  = *(const short8*)(&As[wm + mi * 16 + fr][fk]);
    #pragma unroll
    for (int ni = 0; ni < 4; ++ni) {
      bfx[ni] = *(const short8*)(&Bsx[wn + ni * 16 + fr][fk]);
      bfg[ni] = *(const short8*)(&Bsg[wn + ni * 16 + fr][fk]);
    }
    #pragma unroll
    for (int mi = 0; mi < 4; ++mi)
      #pragma unroll
      for (int ni = 0; ni < 4; ++ni) {
        accx[mi][ni] = __builtin_amdgcn_mfma_f32_16x16x32_bf16(af[mi], bfx[ni], accx[mi][ni], 0, 0, 0);
        accg[mi][ni] = __builtin_amdgcn_mfma_f32_16x16x32_bf16(af[mi], bfg[ni], accg[mi][ni], 0, 0, 0);
      }
    __syncthreads();
  }

  const int fq = (lane >> 4) * 4;
  #pragma unroll
  for (int mi = 0; mi < 4; ++mi)
    #pragma unroll
    for (int rr = 0; rr < 4; ++rr) {
      int gm = bm + wm + mi * 16 + fq + rr;
      #pragma unroll
      for (int ni = 0; ni < 4; ++ni) {
        int col = bn + wn + ni * 16 + fr;
        float xx = accx[mi][ni][rr] + bx[col];
        float g  = accg[mi][ni][rr] + bg[col];
        float t  = tanhf(0.7978845608f * g * (1.0f + 0.044715f * g * g));
        outB[(size_t)gm * N + col] = f2bf(xx * 0.5f * g * (1.0f + t));
      }
    }
}

// ---------------------------------------------------------------- attention
// MFMA flash attention. 4 waves x 32 q-rows = 128 q/block, KVBLK=64.
// QK^T: A=Q,B=K (d padded to 96 with zeros), S C-layout: row q=(lg*4+r)+16mt,
// col kv=l15+16nt. Softmax row-stats via shfl_xor{1,2,4,8}. P -> per-wave LDS
// (bf16) -> re-read as A-frags. PV: B=V from transposed Vt[d][kv].
#define KVB 64

__global__ __launch_bounds__(256) void attn_mfma_kernel(
    const ushort* __restrict__ Qp, int rsq,
    const ushort* __restrict__ Kp, const ushort* __restrict__ Vp, int rskv,
    ushort* __restrict__ O, int Sq, int Sk)
{
  __shared__ ushort Ks[KVB][104];   // kv x d (d 0..95, 80..95 zeroed; +8 pad)
  __shared__ ushort Vt[80][72];     // d x kv (+8 pad)
  __shared__ ushort Ps[4][32][72];  // per-wave P tile (+8 pad)
  const int tid  = threadIdx.x;
  const int lane = tid & 63;
  const int w    = tid >> 6;
  const int l15  = lane & 15;
  const int lg   = lane >> 4;
  const int nqt  = Sq >> 7;
  const int qt   = blockIdx.x % nqt;
  const int bh   = blockIdx.x / nqt;
  const int h    = bh & (HD - 1);
  const int b    = bh / HD;
  const int q0   = qt * 128 + w * 32;
  const float scale = 0.11180339887498949f;  // 80^-0.5

  // Q fragments (registers, zero-padded d 80..95)
  short8 qf[2][3];
  #pragma unroll
  for (int mt = 0; mt < 2; ++mt)
    #pragma unroll
    for (int kc = 0; kc < 3; ++kc) {
      int d0 = kc * 32 + lg * 8;
      if (d0 < DHD)
        qf[mt][kc] = *(const short8*)(Qp + (size_t)(b * Sq + q0 + mt * 16 + l15) * rsq + h * DHD + d0);
      else
        qf[mt][kc] = (short8){0, 0, 0, 0, 0, 0, 0, 0};
    }

  floatx4 oa[2][5];
  #pragma unroll
  for (int mt = 0; mt < 2; ++mt)
    #pragma unroll
    for (int nt = 0; nt < 5; ++nt) oa[mt][nt] = (floatx4){0.f, 0.f, 0.f, 0.f};
  float m[2][4], lsum[2][4];
  #pragma unroll
  for (int mt = 0; mt < 2; ++mt)
    #pragma unroll
    for (int r = 0; r < 4; ++r) { m[mt][r] = -1e30f; lsum[mt][r] = 0.f; }

  // zero the d=80..95 pad of Ks once
  for (int c = tid; c < 128; c += 256)
    *(uint4*)(&Ks[c >> 1][80 + (c & 1) * 8]) = make_uint4(0u, 0u, 0u, 0u);

  for (int kt = 0; kt < Sk; kt += KVB) {
    __syncthreads();
    // stage K [64][80]
    for (int c = tid; c < 320; c += 256) {
      int row = c / 5, sub = c % 5;
      int kvg = kt + row;
      uint4 v = make_uint4(0u, 0u, 0u, 0u);
      if (kvg < Sk) v = *(const uint4*)(Kp + (size_t)(b * Sk + kvg) * rskv + h * DHD + sub * 8);
      *(uint4*)(&Ks[row][sub * 8]) = v;
    }
    // stage V transposed: Vt[d][kv]
    for (int idx = tid; idx < 2560; idx += 256) {
      int d = idx % 80, kv2 = (idx / 80) * 2;
      int kvg = kt + kv2;
      uint pair = 0;
      if (kvg < Sk)     pair  = (uint)Vp[(size_t)(b * Sk + kvg) * rskv + h * DHD + d];
      if (kvg + 1 < Sk) pair |= ((uint)Vp[(size_t)(b * Sk + kvg + 1) * rskv + h * DHD + d]) << 16;
      *(uint*)(&Vt[d][kv2]) = pair;
    }
    __syncthreads();

    // QK^T
    short8 kf[4][3];
    #pragma unroll
    for (int nt = 0; nt < 4; ++nt)
      #pragma unroll
      for (int kc = 0; kc < 3; ++kc)
        kf[nt][kc] = *(const short8*)(&Ks[nt * 16 + l15][kc * 32 + lg * 8]);
    floatx4 s[2][4];
    #pragma unroll
    for (int mt = 0; mt < 2; ++mt)
      #pragma unroll
      for (int nt = 0; nt < 4; ++nt) s[mt][nt] = (floatx4){0.f, 0.f, 0.f, 0.f};
    #pragma unroll
    for (int mt = 0; mt < 2; ++mt)
      #pragma unroll
      for (int nt = 0; nt < 4; ++nt)
        #pragma unroll
        for (int kc = 0; kc < 3; ++kc)
          s[mt][nt] = __builtin_amdgcn_mfma_f32_16x16x32_bf16(qf[mt][kc], kf[nt][kc], s[mt][nt], 0, 0, 0);

    // online softmax (rows are lane-local per (lg, r); reduce over l15)
    #pragma unroll
    for (int mt = 0; mt < 2; ++mt)
      #pragma unroll
      for (int r = 0; r < 4; ++r) {
        float sv[4];
        #pragma unroll
        for (int nt = 0; nt < 4; ++nt) {
          float t = s[mt][nt][r] * scale;
          sv[nt] = (kt + nt * 16 + l15 < Sk) ? t : -1e30f;
        }
        float mx = fmaxf(fmaxf(sv[0], sv[1]), fmaxf(sv[2], sv[3]));
        mx = fmaxf(mx, __shfl_xor(mx, 1));
        mx = fmaxf(mx, __shfl_xor(mx, 2));
        mx = fmaxf(mx, __shfl_xor(mx, 4));
        mx = fmaxf(mx, __shfl_xor(mx, 8));
        float mn = fmaxf(m[mt][r], mx);
        float al = __expf(m[mt][r] - mn);
        m[mt][r] = mn;
        float lt = 0.f;
        #pragma unroll
        for (int nt = 0; nt < 4; ++nt) {
          float p = __expf(sv[nt] - mn);
          lt += p;
          Ps[w][mt * 16 + lg * 4 + r][nt * 16 + l15] = f2bf(p);
        }
        lt += __shfl_xor(lt, 1);
        lt += __shfl_xor(lt, 2);
        lt += __shfl_xor(lt, 4);
        lt += __shfl_xor(lt, 8);
        lsum[mt][r] = lsum[mt][r] * al + lt;
        #pragma unroll
        for (int nt = 0; nt < 5; ++nt) oa[mt][nt][r] *= al;
      }

    // PV (Ps is wave-private; compiler orders ds_write->ds_read)
    short8 pf[2][2];
    #pragma unroll
    for (int mt = 0; mt < 2; ++mt)
      #pragma unroll
      for (int kc2 = 0; kc2 < 2; ++kc2)
        pf[mt][kc2] = *(const short8*)(&Ps[w][mt * 16 + l15][kc2 * 32 + lg * 8]);
    #pragma unroll
    for (int kc2 = 0; kc2 < 2; ++kc2)
      #pragma unroll
      for (int nt = 0; nt < 5; ++nt) {
        short8 vf = *(const short8*)(&Vt[nt * 16 + l15][kc2 * 32 + lg * 8]);
        #pragma unroll
        for (int mt = 0; mt < 2; ++mt)
          oa[mt][nt] = __builtin_amdgcn_mfma_f32_16x16x32_bf16(pf[mt][kc2], vf, oa[mt][nt], 0, 0, 0);
      }
  }

  #pragma unroll
  for (int mt = 0; mt < 2; ++mt)
    #pragma unroll
    for (int r = 0; r < 4; ++r) {
      float inv = 1.f / lsum[mt][r];
      size_t row = (size_t)(b * Sq + q0 + mt * 16 + lg * 4 + r) * CCH + h * DHD;
      #pragma unroll
      for (int nt = 0; nt < 5; ++nt)
        O[row + nt * 16 + l15] = f2bf(oa[mt][nt][r] * inv);
    }
}

// ---------------------------------------------------------------- norms
__global__ __launch_bounds__(256) void layernorm_kernel(
    const float* __restrict__ X, const float* __restrict__ g,
    const float* __restrict__ bt, ushort* __restrict__ out)
{
  int row  = blockIdx.x * 4 + (threadIdx.x >> 6);
  int lane = threadIdx.x & 63;
  const float* xr = X + (size_t)row * CCH;
  float v[10];
  float s = 0.f, ss = 0.f;
  #pragma unroll
  for (int i = 0; i < 10; ++i) {
    float x = xr[lane + i * 64];
    v[i] = x; s += x; ss += x * x;
  }
  #pragma unroll
  for (int msk = 1; msk < 64; msk <<= 1) { s += __shfl_xor(s, msk); ss += __shfl_xor(ss, msk); }
  float mean = s * (1.f / 640.f);
  float var  = ss * (1.f / 640.f) - mean * mean;
  float rs   = rsqrtf(var + 1e-5f);
  ushort* orow = out + (size_t)row * CCH;
  #pragma unroll
  for (int i = 0; i < 10; ++i) {
    int c = lane + i * 64;
    orow[c] = f2bf((v[i] - mean) * rs * g[c] + bt[c]);
  }
}

__global__ __launch_bounds__(256) void groupnorm_kernel(
    const float* __restrict__ X, const float* __restrict__ gamma,
    const float* __restrict__ beta, ushort* __restrict__ out)
{
  int b = blockIdx.x >> 5;
  int g = blockIdx.x & 31;
  int tid = threadIdx.x;
  const float* base = X + (size_t)b * SQ * CCH + g * 20;
  float s = 0.f, ss = 0.f;
  for (int p = tid; p < SQ; p += 256) {
    const float* rp = base + (size_t)p * CCH;
    #pragma unroll
    for (int c = 0; c < 20; ++c) { float x = rp[c]; s += x; ss += x * x; }
  }
  #pragma unroll
  for (int msk = 1; msk < 64; msk <<= 1) { s += __shfl_xor(s, msk); ss += __shfl_xor(ss, msk); }
  __shared__ float red[2][4];
  int lane = tid & 63, wv = tid >> 6;
  if (lane == 0) { red[0][wv] = s; red[1][wv] = ss; }
  __syncthreads();
  s  = red[0][0] + red[0][1] + red[0][2] + red[0][3];
  ss = red[1][0] + red[1][1] + red[1][2] + red[1][3];
  float mean = s * (1.f / 20480.f);
  float var  = ss * (1.f / 20480.f) - mean * mean;
  float rstd = rsqrtf(var + 1e-5f);
  ushort* ob = out + (size_t)b * SQ * CCH + g * 20;
  for (int p = tid; p < SQ; p += 256) {
    const float* rp = base + (size_t)p * CCH;
    ushort* op = ob + (size_t)p * CCH;
    #pragma unroll
    for (int c = 0; c < 20; ++c)
      op[c] = f2bf((rp[c] - mean) * rstd * gamma[g * 20 + c] + beta[g * 20 + c]);
  }
}

// ---------------------------------------------------------------- prep
__global__ void transpose_cast_kernel(const float* __restrict__ W, ushort* __restrict__ WT,
                                      int K, int ld, int coff)
{
  int k = blockIdx.x * 256 + threadIdx.x;
  int n = blockIdx.y;
  if (k < K) WT[(size_t)n * K + k] = f2bf(W[(size_t)k * ld + coff + n]);
}

__global__ void cast_kernel(const float* __restrict__ X, ushort* __restrict__ Y, int n)
{
  int i = blockIdx.x * 256 + threadIdx.x;
  if (i < n) Y[i] = f2bf(X[i]);
}

// ---------------------------------------------------------------- host
static inline void gemm(hipStream_t st, const ushort* A, const ushort* BT,
                        const float* bias, const float* res,
                        float* outF, ushort* outB, int M, int N, int K)
{
  dim3 g((M + 127) / 128, N / 128);
  gemm_bf16_kernel<<<g, dim3(256), 0, st>>>(A, BT, bias, res, outF, outB, M, N, K);
}

extern "C" void kernel_launch(void* const* d_in, const int* in_sizes, int n_in,
                              void* d_out, int out_size, void* d_ws, size_t ws_size,
                              hipStream_t stream)
{
  const float* inputs  = (const float*)d_in[0];
  const float* context = (const float*)d_in[1];
  const float* gn_g    = (const float*)d_in[2];
  const float* gn_b    = (const float*)d_in[3];
  const float* w_proj1 = (const float*)d_in[4];
  const float* b_proj1 = (const float*)d_in[5];
  const float* ln1_g   = (const float*)d_in[6];
  const float* ln1_b   = (const float*)d_in[7];
  const float* wq1     = (const float*)d_in[8];
  const float* wk1     = (const float*)d_in[9];
  const float* wv1     = (const float*)d_in[10];
  const float* wo1     = (const float*)d_in[11];
  const float* bo1     = (const float*)d_in[12];
  const float* ln2_g   = (const float*)d_in[13];
  const float* ln2_b   = (const float*)d_in[14];
  const float* wq2     = (const float*)d_in[15];
  const float* wk2     = (const float*)d_in[16];
  const float* wv2     = (const float*)d_in[17];
  const float* wo2     = (const float*)d_in[18];
  const float* bo2     = (const float*)d_in[19];
  const float* ln3_g   = (const float*)d_in[20];
  const float* ln3_b   = (const float*)d_in[21];
  const float* w_geglu = (const float*)d_in[22];
  const float* b_geglu = (const float*)d_in[23];
  const float* w_ffout = (const float*)d_in[24];
  const float* b_ffout = (const float*)d_in[25];
  const float* w_proj2 = (const float*)d_in[26];
  const float* b_proj2 = (const float*)d_in[27];

  char* p = (char*)d_ws;
  auto alloc = [&](size_t bytes) -> char* {
    char* r = p; p += (bytes + 255) & ~(size_t)255; return r;
  };
  ushort* wT_p1   = (ushort*)alloc(640 * 640 * 2);
  ushort* wT_qkv1 = (ushort*)alloc((size_t)1920 * 640 * 2);
  ushort* wT_o1   = (ushort*)alloc(640 * 640 * 2);
  ushort* wT_q2   = (ushort*)alloc(640 * 640 * 2);
  ushort* wT_kv2  = (ushort*)alloc((size_t)1280 * 768 * 2);
  ushort* wT_o2   = (ushort*)alloc(640 * 640 * 2);
  ushort* wT_gx   = (ushort*)alloc((size_t)2560 * 640 * 2);
  ushort* wT_gg   = (ushort*)alloc((size_t)2560 * 640 * 2);
  ushort* wT_ff   = (ushort*)alloc((size_t)640 * 2560 * 2);
  ushort* wT_p2   = (ushort*)alloc(640 * 640 * 2);
  ushort* ctxb    = (ushort*)alloc((size_t)616 * 768 * 2);
  float*  x       = (float*)alloc((size_t)8192 * 640 * 4);
  ushort* lnb     = (ushort*)alloc((size_t)8192 * 640 * 2);
  ushort* R       = (ushort*)alloc((size_t)8192 * 2560 * 2);  // qkvb / cross-q / hb
  ushort* kvb     = (ushort*)alloc((size_t)616 * 1280 * 2);
  ushort* qkvb = R;      // self q/k/v [8192][1920]
  ushort* qbx  = R;      // cross q [8192][640] (self qkv dead)
  ushort* hb   = R;      // GEGLU out [8192][2560] (cross q dead)
  ushort* ab   = lnb;    // attn out aliases lnb (dead after consuming GEMM)

  auto T = [&](const float* W, ushort* WT, int K, int Nout, int ld, int coff) {
    dim3 g((K + 255) / 256, Nout);
    transpose_cast_kernel<<<g, dim3(256), 0, stream>>>(W, WT, K, ld, coff);
  };
  T(w_proj1, wT_p1, 640, 640, 640, 0);
  T(wq1, wT_qkv1,              640, 640, 640, 0);
  T(wk1, wT_qkv1 + 640 * 640,  640, 640, 640, 0);
  T(wv1, wT_qkv1 + 1280 * 640, 640, 640, 640, 0);
  T(wo1, wT_o1, 640, 640, 640, 0);
  T(wq2, wT_q2, 640, 640, 640, 0);
  T(wk2, wT_kv2,             768, 640, 640, 0);
  T(wv2, wT_kv2 + 640 * 768, 768, 640, 640, 0);
  T(wo2, wT_o2, 640, 640, 640, 0);
  T(w_geglu, wT_gx, 640, 2560, 5120, 0);
  T(w_geglu, wT_gg, 640, 2560, 5120, 2560);
  T(w_ffout, wT_ff, 2560, 640, 640, 0);
  T(w_proj2, wT_p2, 640, 640, 640, 0);
  cast_kernel<<<dim3((616 * 768 + 255) / 256), dim3(256), 0, stream>>>(context, ctxb, 616 * 768);

  // GN -> proj1
  groupnorm_kernel<<<dim3(256), dim3(256), 0, stream>>>(inputs, gn_g, gn_b, lnb);
  gemm(stream, lnb, wT_p1, b_proj1, nullptr, x, nullptr, 8192, 640, 640);

  // self-attention
  layernorm_kernel<<<dim3(2048), dim3(256), 0, stream>>>(x, ln1_g, ln1_b, lnb);
  gemm(stream, lnb, wT_qkv1, nullptr, nullptr, nullptr, qkvb, 8192, 1920, 640);
  attn_mfma_kernel<<<dim3(512), dim3(256), 0, stream>>>(qkvb, 1920, qkvb + 640, qkvb + 1280, 1920, ab, 1024, 1024);
  gemm(stream, ab, wT_o1, bo1, x, x, nullptr, 8192, 640, 640);

  // cross-attention
  layernorm_kernel<<<dim3(2048), dim3(256), 0, stream>>>(x, ln2_g, ln2_b, lnb);
  gemm(stream, lnb, wT_q2, nullptr, nullptr, nullptr, qbx, 8192, 640, 640);
  gemm(stream, ctxb, wT_kv2, nullptr, nullptr, nullptr, kvb, 616, 1280, 768);
  attn_mfma_kernel<<<dim3(512), dim3(256), 0, stream>>>(qbx, 640, kvb, kvb + 640, 1280, ab, 1024, 77);
  gemm(stream, ab, wT_o2, bo2, x, x, nullptr, 8192, 640, 640);

  // GEGLU FF
  layernorm_kernel<<<dim3(2048), dim3(256), 0, stream>>>(x, ln3_g, ln3_b, lnb);
  gemm_geglu_kernel<<<dim3(64, 20), dim3(256), 0, stream>>>(lnb, wT_gx, wT_gg, b_geglu, b_geglu + 2560, hb, 8192, 2560, 640);
  gemm(stream, hb, wT_ff, b_ffout, x, x, nullptr, 8192, 640, 2560);

  // proj2 + input residual
  cast_kernel<<<dim3((8192 * 640 + 255) / 256), dim3(256), 0, stream>>>(x, lnb, 8192 * 640);
  gemm(stream, lnb, wT_p2, b_proj2, inputs, (float*)d_out, nullptr, 8192, 640, 640);
}

// Round 3
// 763.684 us; speedup vs baseline: 2.0270x; 1.0354x over previous
//
#include <hip/hip_runtime.h>
#include <hip/hip_bf16.h>

// SpatialTransformer on MI355X. Round 2: single-barrier double-buffered GEMM
// K-loop (stage overlaps MFMA), GEGLU split to fix the 1-wave/SIMD VGPR cliff,
// tiled weight transpose, vectorized casts.

#define HD 8
#define DHD 80
#define CCH 640
#define SQ 1024

using short8  = __attribute__((ext_vector_type(8))) short;
using floatx4 = __attribute__((ext_vector_type(4))) float;

__device__ __forceinline__ float bf2f(ushort u) {
  union { unsigned int i; float f; } v; v.i = ((unsigned int)u) << 16; return v.f;
}
__device__ __forceinline__ ushort f2bf(float f) {
  union { float f; unsigned int i; } v; v.f = f;
  unsigned int r = v.i + 0x7FFFu + ((v.i >> 16) & 1u);
  return (ushort)(r >> 16);
}

typedef const __attribute__((address_space(1))) void* gas_ptr;
typedef __attribute__((address_space(3))) void* las_ptr;
__device__ __forceinline__ void gload_lds16(const void* g, void* l) {
  __builtin_amdgcn_global_load_lds((gas_ptr)g, (las_ptr)l, 16, 0, 0);
}

// ---------------------------------------------------------------- GEMM
// C[M,N] = A[M,K]@BT[N,K]^T (+bias)(*gelu(aux))(+res) -> outF/outB.
// 128x128 tile, BK=32, 4 waves 2x2, wave 64x64 = 4x4 mfma 16x16x32.
// Double-buffered LDS, ONE barrier per K-step: stage(next) issued before
// ds_read+MFMA(cur); __syncthreads' vmcnt(0)+lgkmcnt(0) drain is the wait.
__global__ __launch_bounds__(256) void gemm_bf16_kernel(
    const ushort* __restrict__ A, const ushort* __restrict__ BT,
    const float* __restrict__ bias, const float* __restrict__ res,
    const ushort* __restrict__ aux, float* __restrict__ outF,
    ushort* __restrict__ outB, int M, int N, int K)
{
  __shared__ ushort As[2][128][32];
  __shared__ ushort Bs[2][128][32];
  const int tid  = threadIdx.x;
  const int lane = tid & 63;
  const int wave = tid >> 6;
  const int wm = (wave >> 1) * 64, wn = (wave & 1) * 64;
  const int bm = blockIdx.x * 128, bn = blockIdx.y * 128;
  const int fr = lane & 15, fk = (lane >> 4) * 8;
  const bool full = (bm + 128 <= M);
  const int nt = K >> 5;

  floatx4 acc[4][4];
  #pragma unroll
  for (int i = 0; i < 4; ++i)
    #pragma unroll
    for (int j = 0; j < 4; ++j) acc[i][j] = (floatx4){0.f, 0.f, 0.f, 0.f};

  // fast-path staging pointers (per-lane): row = base + lane>>2, col = (lane&3)*8
  const int lr = lane >> 2, lc = (lane & 3) * 8;
  const ushort* pA0 = A  + (size_t)(bm + wave * 16 + lr) * K + lc;
  const ushort* pA1 = pA0 + (size_t)64 * K;
  const ushort* pB0 = BT + (size_t)(bn + wave * 16 + lr) * K + lc;
  const ushort* pB1 = pB0 + (size_t)64 * K;
  // tail-path
  const int r0 = tid >> 2, c0 = (tid & 3) * 8;

  auto stage = [&](int nb, int t) {
    const int kt = t * 32;
    if (full) {
      gload_lds16(pA0 + kt, &As[nb][wave * 16][0]);
      gload_lds16(pA1 + kt, &As[nb][wave * 16 + 64][0]);
      gload_lds16(pB0 + kt, &Bs[nb][wave * 16][0]);
      gload_lds16(pB1 + kt, &Bs[nb][wave * 16 + 64][0]);
    } else {
      #pragma unroll
      for (int it = 0; it < 2; ++it) {
        int r = r0 + it * 64;
        int gm = bm + r;
        uint4 va = make_uint4(0u, 0u, 0u, 0u);
        if (gm < M) va = *(const uint4*)(A + (size_t)gm * K + kt + c0);
        *(uint4*)(&As[nb][r][c0]) = va;
        int gn = bn + r;
        uint4 vb = make_uint4(0u, 0u, 0u, 0u);
        if (gn < N) vb = *(const uint4*)(BT + (size_t)gn * K + kt + c0);
        *(uint4*)(&Bs[nb][r][c0]) = vb;
      }
    }
  };

  stage(0, 0);
  __syncthreads();
  int cur = 0;
  for (int t = 0; t < nt; ++t) {
    if (t + 1 < nt) stage(cur ^ 1, t + 1);
    short8 af[4], bfr[4];
    #pragma unroll
    for (int mi = 0; mi < 4; ++mi) af[mi]  = *(const short8*)(&As[cur][wm + mi * 16 + fr][fk]);
    #pragma unroll
    for (int ni = 0; ni < 4; ++ni) bfr[ni] = *(const short8*)(&Bs[cur][wn + ni * 16 + fr][fk]);
    #pragma unroll
    for (int mi = 0; mi < 4; ++mi)
      #pragma unroll
      for (int ni = 0; ni < 4; ++ni)
        acc[mi][ni] = __builtin_amdgcn_mfma_f32_16x16x32_bf16(af[mi], bfr[ni], acc[mi][ni], 0, 0, 0);
    __syncthreads();
    cur ^= 1;
  }

  const int fq = (lane >> 4) * 4;
  #pragma unroll
  for (int mi = 0; mi < 4; ++mi)
    #pragma unroll
    for (int rr = 0; rr < 4; ++rr) {
      int gm = bm + wm + mi * 16 + fq + rr;
      if (gm >= M) continue;
      #pragma unroll
      for (int ni = 0; ni < 4; ++ni) {
        int col = bn + wn + ni * 16 + fr;
        float v = acc[mi][ni][rr];
        if (bias) v += bias[col];
        if (aux) {  // GEGLU: v(=xx+bias) * gelu_tanh(gate)
          float g = bf2f(aux[(size_t)gm * N + col]);
          float t = tanhf(0.7978845608f * g * (1.0f + 0.044715f * g * g));
          v = v * 0.5f * g * (1.0f + t);
        }
        if (res) v += res[(size_t)gm * N + col];
        size_t o = (size_t)gm * N + col;
        if (outF) outF[o] = v;
        if (outB) outB[o] = f2bf(v);
      }
    }
}

// ---------------------------------------------------------------- attention
// MFMA flash attention. 4 waves x 32 q-rows = 128 q/block, KVBLK=64.
#define KVB 64

__global__ __launch_bounds__(256) void attn_mfma_kernel(
    const ushort* __restrict__ Qp, int rsq,
    const ushort* __restrict__ Kp, const ushort* __restrict__ Vp, int rskv,
    ushort* __restrict__ O, int Sq, int Sk)
{
  __shared__ ushort Ks[KVB][104];   // kv x d (d 0..95, 80..95 zeroed; +8 pad)
  __shared__ ushort Vt[80][72];     // d x kv (+8 pad)
  __shared__ ushort Ps[4][32][72];  // per-wave P tile (+8 pad)
  const int tid  = threadIdx.x;
  const int lane = tid & 63;
  const int w    = tid >> 6;
  const int l15  = lane & 15;
  const int lg   = lane >> 4;
  const int nqt  = Sq >> 7;
  const int qt   = blockIdx.x % nqt;
  const int bh   = blockIdx.x / nqt;
  const int h    = bh & (HD - 1);
  const int b    = bh / HD;
  const int q0   = qt * 128 + w * 32;
  const float scale = 0.11180339887498949f;  // 80^-0.5

  short8 qf[2][3];
  #pragma unroll
  for (int mt = 0; mt < 2; ++mt)
    #pragma unroll
    for (int kc = 0; kc < 3; ++kc) {
      int d0 = kc * 32 + lg * 8;
      if (d0 < DHD)
        qf[mt][kc] = *(const short8*)(Qp + (size_t)(b * Sq + q0 + mt * 16 + l15) * rsq + h * DHD + d0);
      else
        qf[mt][kc] = (short8){0, 0, 0, 0, 0, 0, 0, 0};
    }

  floatx4 oa[2][5];
  #pragma unroll
  for (int mt = 0; mt < 2; ++mt)
    #pragma unroll
    for (int nt = 0; nt < 5; ++nt) oa[mt][nt] = (floatx4){0.f, 0.f, 0.f, 0.f};
  float m[2][4], lsum[2][4];
  #pragma unroll
  for (int mt = 0; mt < 2; ++mt)
    #pragma unroll
    for (int r = 0; r < 4; ++r) { m[mt][r] = -1e30f; lsum[mt][r] = 0.f; }

  for (int c = tid; c < 128; c += 256)
    *(uint4*)(&Ks[c >> 1][80 + (c & 1) * 8]) = make_uint4(0u, 0u, 0u, 0u);

  for (int kt = 0; kt < Sk; kt += KVB) {
    __syncthreads();
    for (int c = tid; c < 320; c += 256) {
      int row = c / 5, sub = c % 5;
      int kvg = kt + row;
      uint4 v = make_uint4(0u, 0u, 0u, 0u);
      if (kvg < Sk) v = *(const uint4*)(Kp + (size_t)(b * Sk + kvg) * rskv + h * DHD + sub * 8);
      *(uint4*)(&Ks[row][sub * 8]) = v;
    }
    for (int idx = tid; idx < 2560; idx += 256) {
      int d = idx % 80, kv2 = (idx / 80) * 2;
      int kvg = kt + kv2;
      uint pair = 0;
      if (kvg < Sk)     pair  = (uint)Vp[(size_t)(b * Sk + kvg) * rskv + h * DHD + d];
      if (kvg + 1 < Sk) pair |= ((uint)Vp[(size_t)(b * Sk + kvg + 1) * rskv + h * DHD + d]) << 16;
      *(uint*)(&Vt[d][kv2]) = pair;
    }
    __syncthreads();

    short8 kf[4][3];
    #pragma unroll
    for (int nt = 0; nt < 4; ++nt)
      #pragma unroll
      for (int kc = 0; kc < 3; ++kc)
        kf[nt][kc] = *(const short8*)(&Ks[nt * 16 + l15][kc * 32 + lg * 8]);
    floatx4 s[2][4];
    #pragma unroll
    for (int mt = 0; mt < 2; ++mt)
      #pragma unroll
      for (int nt = 0; nt < 4; ++nt) s[mt][nt] = (floatx4){0.f, 0.f, 0.f, 0.f};
    #pragma unroll
    for (int mt = 0; mt < 2; ++mt)
      #pragma unroll
      for (int nt = 0; nt < 4; ++nt)
        #pragma unroll
        for (int kc = 0; kc < 3; ++kc)
          s[mt][nt] = __builtin_amdgcn_mfma_f32_16x16x32_bf16(qf[mt][kc], kf[nt][kc], s[mt][nt], 0, 0, 0);

    #pragma unroll
    for (int mt = 0; mt < 2; ++mt)
      #pragma unroll
      for (int r = 0; r < 4; ++r) {
        float sv[4];
        #pragma unroll
        for (int nt = 0; nt < 4; ++nt) {
          float t = s[mt][nt][r] * scale;
          sv[nt] = (kt + nt * 16 + l15 < Sk) ? t : -1e30f;
        }
        float mx = fmaxf(fmaxf(sv[0], sv[1]), fmaxf(sv[2], sv[3]));
        mx = fmaxf(mx, __shfl_xor(mx, 1));
        mx = fmaxf(mx, __shfl_xor(mx, 2));
        mx = fmaxf(mx, __shfl_xor(mx, 4));
        mx = fmaxf(mx, __shfl_xor(mx, 8));
        float mn = fmaxf(m[mt][r], mx);
        float al = __expf(m[mt][r] - mn);
        m[mt][r] = mn;
        float lt = 0.f;
        #pragma unroll
        for (int nt = 0; nt < 4; ++nt) {
          float p = __expf(sv[nt] - mn);
          lt += p;
          Ps[w][mt * 16 + lg * 4 + r][nt * 16 + l15] = f2bf(p);
        }
        lt += __shfl_xor(lt, 1);
        lt += __shfl_xor(lt, 2);
        lt += __shfl_xor(lt, 4);
        lt += __shfl_xor(lt, 8);
        lsum[mt][r] = lsum[mt][r] * al + lt;
        #pragma unroll
        for (int nt = 0; nt < 5; ++nt) oa[mt][nt][r] *= al;
      }

    short8 pf[2][2];
    #pragma unroll
    for (int mt = 0; mt < 2; ++mt)
      #pragma unroll
      for (int kc2 = 0; kc2 < 2; ++kc2)
        pf[mt][kc2] = *(const short8*)(&Ps[w][mt * 16 + l15][kc2 * 32 + lg * 8]);
    #pragma unroll
    for (int kc2 = 0; kc2 < 2; ++kc2)
      #pragma unroll
      for (int nt = 0; nt < 5; ++nt) {
        short8 vf = *(const short8*)(&Vt[nt * 16 + l15][kc2 * 32 + lg * 8]);
        #pragma unroll
        for (int mt = 0; mt < 2; ++mt)
          oa[mt][nt] = __builtin_amdgcn_mfma_f32_16x16x32_bf16(pf[mt][kc2], vf, oa[mt][nt], 0, 0, 0);
      }
  }

  #pragma unroll
  for (int mt = 0; mt < 2; ++mt)
    #pragma unroll
    for (int r = 0; r < 4; ++r) {
      float inv = 1.f / lsum[mt][r];
      size_t row = (size_t)(b * Sq + q0 + mt * 16 + lg * 4 + r) * CCH + h * DHD;
      #pragma unroll
      for (int nt = 0; nt < 5; ++nt)
        O[row + nt * 16 + l15] = f2bf(oa[mt][nt][r] * inv);
    }
}

// ---------------------------------------------------------------- norms
__global__ __launch_bounds__(256) void layernorm_kernel(
    const float* __restrict__ X, const float* __restrict__ g,
    const float* __restrict__ bt, ushort* __restrict__ out)
{
  int row  = blockIdx.x * 4 + (threadIdx.x >> 6);
  int lane = threadIdx.x & 63;
  const float* xr = X + (size_t)row * CCH;
  float v[10];
  float s = 0.f, ss = 0.f;
  #pragma unroll
  for (int i = 0; i < 10; ++i) {
    float x = xr[lane + i * 64];
    v[i] = x; s += x; ss += x * x;
  }
  #pragma unroll
  for (int msk = 1; msk < 64; msk <<= 1) { s += __shfl_xor(s, msk); ss += __shfl_xor(ss, msk); }
  float mean = s * (1.f / 640.f);
  float var  = ss * (1.f / 640.f) - mean * mean;
  float rs   = rsqrtf(var + 1e-5f);
  ushort* orow = out + (size_t)row * CCH;
  #pragma unroll
  for (int i = 0; i < 10; ++i) {
    int c = lane + i * 64;
    orow[c] = f2bf((v[i] - mean) * rs * g[c] + bt[c]);
  }
}

__global__ __launch_bounds__(256) void groupnorm_kernel(
    const float* __restrict__ X, const float* __restrict__ gamma,
    const float* __restrict__ beta, ushort* __restrict__ out)
{
  int b = blockIdx.x >> 5;
  int g = blockIdx.x & 31;
  int tid = threadIdx.x;
  const float* base = X + (size_t)b * SQ * CCH + g * 20;
  float s = 0.f, ss = 0.f;
  for (int p = tid; p < SQ; p += 256) {
    const float* rp = base + (size_t)p * CCH;
    #pragma unroll
    for (int c = 0; c < 20; ++c) { float x = rp[c]; s += x; ss += x * x; }
  }
  #pragma unroll
  for (int msk = 1; msk < 64; msk <<= 1) { s += __shfl_xor(s, msk); ss += __shfl_xor(ss, msk); }
  __shared__ float red[2][4];
  int lane = tid & 63, wv = tid >> 6;
  if (lane == 0) { red[0][wv] = s; red[1][wv] = ss; }
  __syncthreads();
  s  = red[0][0] + red[0][1] + red[0][2] + red[0][3];
  ss = red[1][0] + red[1][1] + red[1][2] + red[1][3];
  float mean = s * (1.f / 20480.f);
  float var  = ss * (1.f / 20480.f) - mean * mean;
  float rstd = rsqrtf(var + 1e-5f);
  ushort* ob = out + (size_t)b * SQ * CCH + g * 20;
  for (int p = tid; p < SQ; p += 256) {
    const float* rp = base + (size_t)p * CCH;
    ushort* op = ob + (size_t)p * CCH;
    #pragma unroll
    for (int c = 0; c < 20; ++c)
      op[c] = f2bf((rp[c] - mean) * rstd * gamma[g * 20 + c] + beta[g * 20 + c]);
  }
}

// ---------------------------------------------------------------- prep
// Tiled 32x32 transpose+cast: WT[n*K + k] = bf16(W[k*ld + coff + n])
__global__ __launch_bounds__(256) void transpose_cast_kernel(
    const float* __restrict__ W, ushort* __restrict__ WT, int K, int ld, int coff)
{
  __shared__ float tile[32][33];
  const int tx = threadIdx.x, ty = threadIdx.y;
  const int k0 = blockIdx.x * 32, n0 = blockIdx.y * 32;
  #pragma unroll
  for (int i = 0; i < 4; ++i)
    tile[ty + i * 8][tx] = W[(size_t)(k0 + ty + i * 8) * ld + coff + n0 + tx];
  __syncthreads();
  #pragma unroll
  for (int i = 0; i < 4; ++i)
    WT[(size_t)(n0 + ty + i * 8) * K + k0 + tx] = f2bf(tile[tx][ty + i * 8]);
}

__global__ void cast_kernel(const float* __restrict__ X, ushort* __restrict__ Y, int n)
{
  int i = (blockIdx.x * 256 + threadIdx.x) * 4;
  if (i < n) {
    float4 v = *(const float4*)(X + i);
    ushort4 o;
    o.x = f2bf(v.x); o.y = f2bf(v.y); o.z = f2bf(v.z); o.w = f2bf(v.w);
    *(ushort4*)(Y + i) = o;
  }
}

// ---------------------------------------------------------------- host
static inline void gemm(hipStream_t st, const ushort* A, const ushort* BT,
                        const float* bias, const float* res, const ushort* aux,
                        float* outF, ushort* outB, int M, int N, int K)
{
  dim3 g((M + 127) / 128, N / 128);
  gemm_bf16_kernel<<<g, dim3(256), 0, st>>>(A, BT, bias, res, aux, outF, outB, M, N, K);
}

extern "C" void kernel_launch(void* const* d_in, const int* in_sizes, int n_in,
                              void* d_out, int out_size, void* d_ws, size_t ws_size,
                              hipStream_t stream)
{
  const float* inputs  = (const float*)d_in[0];
  const float* context = (const float*)d_in[1];
  const float* gn_g    = (const float*)d_in[2];
  const float* gn_b    = (const float*)d_in[3];
  const float* w_proj1 = (const float*)d_in[4];
  const float* b_proj1 = (const float*)d_in[5];
  const float* ln1_g   = (const float*)d_in[6];
  const float* ln1_b   = (const float*)d_in[7];
  const float* wq1     = (const float*)d_in[8];
  const float* wk1     = (const float*)d_in[9];
  const float* wv1     = (const float*)d_in[10];
  const float* wo1     = (const float*)d_in[11];
  const float* bo1     = (const float*)d_in[12];
  const float* ln2_g   = (const float*)d_in[13];
  const float* ln2_b   = (const float*)d_in[14];
  const float* wq2     = (const float*)d_in[15];
  const float* wk2     = (const float*)d_in[16];
  const float* wv2     = (const float*)d_in[17];
  const float* wo2     = (const float*)d_in[18];
  const float* bo2     = (const float*)d_in[19];
  const float* ln3_g   = (const float*)d_in[20];
  const float* ln3_b   = (const float*)d_in[21];
  const float* w_geglu = (const float*)d_in[22];
  const float* b_geglu = (const float*)d_in[23];
  const float* w_ffout = (const float*)d_in[24];
  const float* b_ffout = (const float*)d_in[25];
  const float* w_proj2 = (const float*)d_in[26];
  const float* b_proj2 = (const float*)d_in[27];

  char* p = (char*)d_ws;
  auto alloc = [&](size_t bytes) -> char* {
    char* r = p; p += (bytes + 255) & ~(size_t)255; return r;
  };
  ushort* wT_p1   = (ushort*)alloc(640 * 640 * 2);
  ushort* wT_qkv1 = (ushort*)alloc((size_t)1920 * 640 * 2);
  ushort* wT_o1   = (ushort*)alloc(640 * 640 * 2);
  ushort* wT_q2   = (ushort*)alloc(640 * 640 * 2);
  ushort* wT_kv2  = (ushort*)alloc((size_t)1280 * 768 * 2);
  ushort* wT_o2   = (ushort*)alloc(640 * 640 * 2);
  ushort* wT_gx   = (ushort*)alloc((size_t)2560 * 640 * 2);
  ushort* wT_gg   = (ushort*)alloc((size_t)2560 * 640 * 2);
  ushort* wT_ff   = (ushort*)alloc((size_t)640 * 2560 * 2);
  ushort* wT_p2   = (ushort*)alloc(640 * 640 * 2);
  ushort* ctxb    = (ushort*)alloc((size_t)616 * 768 * 2);
  float*  x       = (float*)alloc((size_t)8192 * 640 * 4);
  ushort* lnb     = (ushort*)alloc((size_t)8192 * 640 * 2);
  ushort* R       = (ushort*)alloc((size_t)8192 * 2560 * 2);  // qkv / cross-q / hb
  ushort* gateb   = (ushort*)alloc((size_t)8192 * 2560 * 2);
  ushort* kvb     = (ushort*)alloc((size_t)616 * 1280 * 2);
  ushort* qkvb = R;      // self q/k/v [8192][1920]
  ushort* qbx  = R;      // cross q [8192][640]
  ushort* hb   = R;      // GEGLU out [8192][2560]
  ushort* ab   = lnb;    // attn out aliases lnb

  auto T = [&](const float* W, ushort* WT, int K, int Nout, int ld, int coff) {
    dim3 g(K / 32, Nout / 32);
    transpose_cast_kernel<<<g, dim3(32, 8), 0, stream>>>(W, WT, K, ld, coff);
  };
  T(w_proj1, wT_p1, 640, 640, 640, 0);
  T(wq1, wT_qkv1,              640, 640, 640, 0);
  T(wk1, wT_qkv1 + 640 * 640,  640, 640, 640, 0);
  T(wv1, wT_qkv1 + 1280 * 640, 640, 640, 640, 0);
  T(wo1, wT_o1, 640, 640, 640, 0);
  T(wq2, wT_q2, 640, 640, 640, 0);
  T(wk2, wT_kv2,             768, 640, 640, 0);
  T(wv2, wT_kv2 + 640 * 768, 768, 640, 640, 0);
  T(wo2, wT_o2, 640, 640, 640, 0);
  T(w_geglu, wT_gx, 640, 2560, 5120, 0);
  T(w_geglu, wT_gg, 640, 2560, 5120, 2560);
  T(w_ffout, wT_ff, 2560, 640, 640, 0);
  T(w_proj2, wT_p2, 640, 640, 640, 0);
  cast_kernel<<<dim3((616 * 768 / 4 + 255) / 256), dim3(256), 0, stream>>>(context, ctxb, 616 * 768);

  // GN -> proj1
  groupnorm_kernel<<<dim3(256), dim3(256), 0, stream>>>(inputs, gn_g, gn_b, lnb);
  gemm(stream, lnb, wT_p1, b_proj1, nullptr, nullptr, x, nullptr, 8192, 640, 640);

  // self-attention
  layernorm_kernel<<<dim3(2048), dim3(256), 0, stream>>>(x, ln1_g, ln1_b, lnb);
  gemm(stream, lnb, wT_qkv1, nullptr, nullptr, nullptr, nullptr, qkvb, 8192, 1920, 640);
  attn_mfma_kernel<<<dim3(512), dim3(256), 0, stream>>>(qkvb, 1920, qkvb + 640, qkvb + 1280, 1920, ab, 1024, 1024);
  gemm(stream, ab, wT_o1, bo1, x, nullptr, x, nullptr, 8192, 640, 640);

  // cross-attention
  layernorm_kernel<<<dim3(2048), dim3(256), 0, stream>>>(x, ln2_g, ln2_b, lnb);
  gemm(stream, lnb, wT_q2, nullptr, nullptr, nullptr, nullptr, qbx, 8192, 640, 640);
  gemm(stream, ctxb, wT_kv2, nullptr, nullptr, nullptr, nullptr, kvb, 616, 1280, 768);
  attn_mfma_kernel<<<dim3(512), dim3(256), 0, stream>>>(qbx, 640, kvb, kvb + 640, 1280, ab, 1024, 77);
  gemm(stream, ab, wT_o2, bo2, x, nullptr, x, nullptr, 8192, 640, 640);

  // GEGLU FF (split: gate GEMM, then xx GEMM with fused gelu-aux epilogue)
  layernorm_kernel<<<dim3(2048), dim3(256), 0, stream>>>(x, ln3_g, ln3_b, lnb);
  gemm(stream, lnb, wT_gg, b_geglu + 2560, nullptr, nullptr, nullptr, gateb, 8192, 2560, 640);
  gemm(stream, lnb, wT_gx, b_geglu, nullptr, gateb, nullptr, hb, 8192, 2560, 640);
  gemm(stream, hb, wT_ff, b_ffout, x, nullptr, x, nullptr, 8192, 640, 2560);

  // proj2 + input residual
  cast_kernel<<<dim3((8192 * 640 / 4 + 255) / 256), dim3(256), 0, stream>>>(x, lnb, 8192 * 640);
  gemm(stream, lnb, wT_p2, b_proj2, inputs, nullptr, (float*)d_out, nullptr, 8192, 640, 640);
}

// Round 5
// 664.061 us; speedup vs baseline: 2.3311x; 1.1500x over previous
//
#include <hip/hip_runtime.h>
#include <hip/hip_bf16.h>

// SpatialTransformer on MI355X. Round 5: round-4 occupancy fixes (attn QBLK=64
// -> 4 blocks/CU; BN=64 GEMM for N=640) with round-3's proven workspace
// footprint (no pre-transposed V; in-kernel scalar V transpose staging).

#define HD 8
#define DHD 80
#define CCH 640
#define SQ 1024

using short8  = __attribute__((ext_vector_type(8))) short;
using floatx4 = __attribute__((ext_vector_type(4))) float;

__device__ __forceinline__ float bf2f(ushort u) {
  union { unsigned int i; float f; } v; v.i = ((unsigned int)u) << 16; return v.f;
}
__device__ __forceinline__ ushort f2bf(float f) {
  union { float f; unsigned int i; } v; v.f = f;
  unsigned int r = v.i + 0x7FFFu + ((v.i >> 16) & 1u);
  return (ushort)(r >> 16);
}

typedef const __attribute__((address_space(1))) void* gas_ptr;
typedef __attribute__((address_space(3))) void* las_ptr;
__device__ __forceinline__ void gload_lds16(const void* g, void* l) {
  __builtin_amdgcn_global_load_lds((gas_ptr)g, (las_ptr)l, 16, 0, 0);
}

// ---------------------------------------------------------------- GEMM
// C[M,N] = A[M,K]@BT[N,K]^T (+bias)(*gelu(aux))(+res). BM=128, BN in {128,64},
// BK=32, 4 waves 2x2 (wave 64 x BN/2). Double-buffered LDS, one barrier/K-step.
template<int BN>
__global__ __launch_bounds__(256) void gemm_bf16_kernel(
    const ushort* __restrict__ A, const ushort* __restrict__ BT,
    const float* __restrict__ bias, const float* __restrict__ res,
    const ushort* __restrict__ aux, float* __restrict__ outF,
    ushort* __restrict__ outB, int M, int N, int K)
{
  constexpr int NT = BN / 32;              // n-tiles per wave
  __shared__ ushort As[2][128][32];
  __shared__ ushort Bs[2][BN][32];
  const int tid  = threadIdx.x;
  const int lane = tid & 63;
  const int wave = tid >> 6;
  const int wm = (wave >> 1) * 64, wn = (wave & 1) * (BN / 2);
  const int bm = blockIdx.x * 128, bn = blockIdx.y * BN;
  const int fr = lane & 15, fk = (lane >> 4) * 8;
  const bool full = (bm + 128 <= M);
  const int nt = K >> 5;

  floatx4 acc[4][NT];
  #pragma unroll
  for (int i = 0; i < 4; ++i)
    #pragma unroll
    for (int j = 0; j < NT; ++j) acc[i][j] = (floatx4){0.f, 0.f, 0.f, 0.f};

  const int lr = lane >> 2, lc = (lane & 3) * 8;
  const ushort* pA0 = A  + (size_t)(bm + wave * 16 + lr) * K + lc;
  const ushort* pA1 = pA0 + (size_t)64 * K;
  const ushort* pB0 = BT + (size_t)(bn + wave * 16 + lr) * K + lc;
  const ushort* pB1 = pB0 + (size_t)64 * K;
  const int r0 = tid >> 2, c0 = (tid & 3) * 8;

  auto stage = [&](int nb, int t) {
    const int kt = t * 32;
    if (full) {
      gload_lds16(pA0 + kt, &As[nb][wave * 16][0]);
      gload_lds16(pA1 + kt, &As[nb][wave * 16 + 64][0]);
      gload_lds16(pB0 + kt, &Bs[nb][wave * 16][0]);
      if (BN == 128) gload_lds16(pB1 + kt, &Bs[nb][wave * 16 + 64][0]);
    } else {
      #pragma unroll
      for (int it = 0; it < 2; ++it) {
        int r = r0 + it * 64;
        int gm = bm + r;
        uint4 va = make_uint4(0u, 0u, 0u, 0u);
        if (gm < M) va = *(const uint4*)(A + (size_t)gm * K + kt + c0);
        *(uint4*)(&As[nb][r][c0]) = va;
        if (r < BN) {
          int gn = bn + r;
          uint4 vb = make_uint4(0u, 0u, 0u, 0u);
          if (gn < N) vb = *(const uint4*)(BT + (size_t)gn * K + kt + c0);
          *(uint4*)(&Bs[nb][r][c0]) = vb;
        }
      }
    }
  };

  stage(0, 0);
  __syncthreads();
  int cur = 0;
  for (int t = 0; t < nt; ++t) {
    if (t + 1 < nt) stage(cur ^ 1, t + 1);
    short8 af[4], bfr[NT];
    #pragma unroll
    for (int mi = 0; mi < 4; ++mi) af[mi]  = *(const short8*)(&As[cur][wm + mi * 16 + fr][fk]);
    #pragma unroll
    for (int ni = 0; ni < NT; ++ni) bfr[ni] = *(const short8*)(&Bs[cur][wn + ni * 16 + fr][fk]);
    #pragma unroll
    for (int mi = 0; mi < 4; ++mi)
      #pragma unroll
      for (int ni = 0; ni < NT; ++ni)
        acc[mi][ni] = __builtin_amdgcn_mfma_f32_16x16x32_bf16(af[mi], bfr[ni], acc[mi][ni], 0, 0, 0);
    __syncthreads();
    cur ^= 1;
  }

  const int fq = (lane >> 4) * 4;
  #pragma unroll
  for (int mi = 0; mi < 4; ++mi)
    #pragma unroll
    for (int rr = 0; rr < 4; ++rr) {
      int gm = bm + wm + mi * 16 + fq + rr;
      if (gm >= M) continue;
      #pragma unroll
      for (int ni = 0; ni < NT; ++ni) {
        int col = bn + wn + ni * 16 + fr;
        float v = acc[mi][ni][rr];
        if (bias) v += bias[col];
        if (aux) {
          float g = bf2f(aux[(size_t)gm * N + col]);
          float t = tanhf(0.7978845608f * g * (1.0f + 0.044715f * g * g));
          v = v * 0.5f * g * (1.0f + t);
        }
        if (res) v += res[(size_t)gm * N + col];
        size_t o = (size_t)gm * N + col;
        if (outF) outF[o] = v;
        if (outB) outB[o] = f2bf(v);
      }
    }
}

// ---------------------------------------------------------------- attention
// MFMA flash attention. 4 waves x 16 q-rows = 64 q/block, KVB=64, grid =
// (Sq/64)*B*H = 1024 -> 4 blocks/CU (LDS 34KB). In-kernel V transpose staging.
#define KVB 64

__global__ __launch_bounds__(256) void attn_mfma_kernel(
    const ushort* __restrict__ Qp, int rsq,
    const ushort* __restrict__ Kp, const ushort* __restrict__ Vp, int rskv,
    ushort* __restrict__ O, int Sq, int Sk)
{
  __shared__ ushort Ks[KVB][104];   // kv x d (d 0..95, 80..95 zeroed; +8 pad)
  __shared__ ushort Vt[80][72];     // d x kv (+8 pad)
  __shared__ ushort Ps[4][16][72];  // per-wave P tile (+8 pad)
  const int tid  = threadIdx.x;
  const int lane = tid & 63;
  const int w    = tid >> 6;
  const int l15  = lane & 15;
  const int lg   = lane >> 4;
  const int nqt  = Sq >> 6;
  const int qt   = blockIdx.x % nqt;
  const int bh   = blockIdx.x / nqt;
  const int h    = bh & (HD - 1);
  const int b    = bh / HD;
  const int q0   = qt * 64 + w * 16;
  const float scale = 0.11180339887498949f;  // 80^-0.5

  // Q fragments (zero-padded d 80..95)
  short8 qf[3];
  #pragma unroll
  for (int kc = 0; kc < 3; ++kc) {
    int d0 = kc * 32 + lg * 8;
    if (d0 < DHD)
      qf[kc] = *(const short8*)(Qp + (size_t)(b * Sq + q0 + l15) * rsq + h * DHD + d0);
    else
      qf[kc] = (short8){0, 0, 0, 0, 0, 0, 0, 0};
  }

  floatx4 oa[5];
  #pragma unroll
  for (int nt = 0; nt < 5; ++nt) oa[nt] = (floatx4){0.f, 0.f, 0.f, 0.f};
  float m[4], lsum[4];
  #pragma unroll
  for (int r = 0; r < 4; ++r) { m[r] = -1e30f; lsum[r] = 0.f; }

  // zero the d=80..95 pad of Ks once
  for (int c = tid; c < 128; c += 256)
    *(uint4*)(&Ks[c >> 1][80 + (c & 1) * 8]) = make_uint4(0u, 0u, 0u, 0u);

  for (int kt = 0; kt < Sk; kt += KVB) {
    __syncthreads();
    // stage K [64][80] (row-major, coalesced 16B)
    for (int c = tid; c < 320; c += 256) {
      int row = c / 5, sub = c % 5;
      int kvg = kt + row;
      uint4 v = make_uint4(0u, 0u, 0u, 0u);
      if (kvg < Sk) v = *(const uint4*)(Kp + (size_t)(b * Sk + kvg) * rskv + h * DHD + sub * 8);
      *(uint4*)(&Ks[row][sub * 8]) = v;
    }
    // stage V transposed in-kernel: Vt[d][kv] (scalar loads, proven path)
    for (int idx = tid; idx < 2560; idx += 256) {
      int d = idx % 80, kv2 = (idx / 80) * 2;
      int kvg = kt + kv2;
      uint pair = 0;
      if (kvg < Sk)     pair  = (uint)Vp[(size_t)(b * Sk + kvg) * rskv + h * DHD + d];
      if (kvg + 1 < Sk) pair |= ((uint)Vp[(size_t)(b * Sk + kvg + 1) * rskv + h * DHD + d]) << 16;
      *(uint*)(&Vt[d][kv2]) = pair;
    }
    __syncthreads();

    // QK^T
    short8 kf[4][3];
    #pragma unroll
    for (int nt = 0; nt < 4; ++nt)
      #pragma unroll
      for (int kc = 0; kc < 3; ++kc)
        kf[nt][kc] = *(const short8*)(&Ks[nt * 16 + l15][kc * 32 + lg * 8]);
    floatx4 s[4];
    #pragma unroll
    for (int nt = 0; nt < 4; ++nt) s[nt] = (floatx4){0.f, 0.f, 0.f, 0.f};
    #pragma unroll
    for (int nt = 0; nt < 4; ++nt)
      #pragma unroll
      for (int kc = 0; kc < 3; ++kc)
        s[nt] = __builtin_amdgcn_mfma_f32_16x16x32_bf16(qf[kc], kf[nt][kc], s[nt], 0, 0, 0);

    const bool masked = (kt + KVB > Sk);
    #pragma unroll
    for (int r = 0; r < 4; ++r) {
      float sv[4];
      #pragma unroll
      for (int nt = 0; nt < 4; ++nt) {
        float t = s[nt][r] * scale;
        sv[nt] = (masked && (kt + nt * 16 + l15 >= Sk)) ? -1e30f : t;
      }
      float mx = fmaxf(fmaxf(sv[0], sv[1]), fmaxf(sv[2], sv[3]));
      mx = fmaxf(mx, __shfl_xor(mx, 1));
      mx = fmaxf(mx, __shfl_xor(mx, 2));
      mx = fmaxf(mx, __shfl_xor(mx, 4));
      mx = fmaxf(mx, __shfl_xor(mx, 8));
      float mn = fmaxf(m[r], mx);
      float al = __expf(m[r] - mn);
      m[r] = mn;
      float lt = 0.f;
      #pragma unroll
      for (int nt = 0; nt < 4; ++nt) {
        float p = __expf(sv[nt] - mn);
        lt += p;
        Ps[w][lg * 4 + r][nt * 16 + l15] = f2bf(p);
      }
      lt += __shfl_xor(lt, 1);
      lt += __shfl_xor(lt, 2);
      lt += __shfl_xor(lt, 4);
      lt += __shfl_xor(lt, 8);
      lsum[r] = lsum[r] * al + lt;
      #pragma unroll
      for (int nt = 0; nt < 5; ++nt) oa[nt][r] *= al;
    }

    // PV (Ps wave-private)
    short8 pf[2];
    #pragma unroll
    for (int kc2 = 0; kc2 < 2; ++kc2)
      pf[kc2] = *(const short8*)(&Ps[w][l15][kc2 * 32 + lg * 8]);
    #pragma unroll
    for (int kc2 = 0; kc2 < 2; ++kc2)
      #pragma unroll
      for (int nt = 0; nt < 5; ++nt) {
        short8 vf = *(const short8*)(&Vt[nt * 16 + l15][kc2 * 32 + lg * 8]);
        oa[nt] = __builtin_amdgcn_mfma_f32_16x16x32_bf16(pf[kc2], vf, oa[nt], 0, 0, 0);
      }
  }

  #pragma unroll
  for (int r = 0; r < 4; ++r) {
    float inv = 1.f / lsum[r];
    size_t row = (size_t)(b * Sq + q0 + lg * 4 + r) * CCH + h * DHD;
    #pragma unroll
    for (int nt = 0; nt < 5; ++nt)
      O[row + nt * 16 + l15] = f2bf(oa[nt][r] * inv);
  }
}

// ---------------------------------------------------------------- norms
__global__ __launch_bounds__(256) void layernorm_kernel(
    const float* __restrict__ X, const float* __restrict__ g,
    const float* __restrict__ bt, ushort* __restrict__ out)
{
  int row  = blockIdx.x * 4 + (threadIdx.x >> 6);
  int lane = threadIdx.x & 63;
  const float* xr = X + (size_t)row * CCH;
  float v[10];
  float s = 0.f, ss = 0.f;
  #pragma unroll
  for (int i = 0; i < 10; ++i) {
    float x = xr[lane + i * 64];
    v[i] = x; s += x; ss += x * x;
  }
  #pragma unroll
  for (int msk = 1; msk < 64; msk <<= 1) { s += __shfl_xor(s, msk); ss += __shfl_xor(ss, msk); }
  float mean = s * (1.f / 640.f);
  float var  = ss * (1.f / 640.f) - mean * mean;
  float rs   = rsqrtf(var + 1e-5f);
  ushort* orow = out + (size_t)row * CCH;
  #pragma unroll
  for (int i = 0; i < 10; ++i) {
    int c = lane + i * 64;
    orow[c] = f2bf((v[i] - mean) * rs * g[c] + bt[c]);
  }
}

__global__ __launch_bounds__(256) void groupnorm_kernel(
    const float* __restrict__ X, const float* __restrict__ gamma,
    const float* __restrict__ beta, ushort* __restrict__ out)
{
  int b = blockIdx.x >> 5;
  int g = blockIdx.x & 31;
  int tid = threadIdx.x;
  const float* base = X + (size_t)b * SQ * CCH + g * 20;
  float s = 0.f, ss = 0.f;
  for (int p = tid; p < SQ; p += 256) {
    const float* rp = base + (size_t)p * CCH;
    #pragma unroll
    for (int c = 0; c < 20; ++c) { float x = rp[c]; s += x; ss += x * x; }
  }
  #pragma unroll
  for (int msk = 1; msk < 64; msk <<= 1) { s += __shfl_xor(s, msk); ss += __shfl_xor(ss, msk); }
  __shared__ float red[2][4];
  int lane = tid & 63, wv = tid >> 6;
  if (lane == 0) { red[0][wv] = s; red[1][wv] = ss; }
  __syncthreads();
  s  = red[0][0] + red[0][1] + red[0][2] + red[0][3];
  ss = red[1][0] + red[1][1] + red[1][2] + red[1][3];
  float mean = s * (1.f / 20480.f);
  float var  = ss * (1.f / 20480.f) - mean * mean;
  float rstd = rsqrtf(var + 1e-5f);
  ushort* ob = out + (size_t)b * SQ * CCH + g * 20;
  for (int p = tid; p < SQ; p += 256) {
    const float* rp = base + (size_t)p * CCH;
    ushort* op = ob + (size_t)p * CCH;
    #pragma unroll
    for (int c = 0; c < 20; ++c)
      op[c] = f2bf((rp[c] - mean) * rstd * gamma[g * 20 + c] + beta[g * 20 + c]);
  }
}

// ---------------------------------------------------------------- prep
__global__ __launch_bounds__(256) void transpose_cast_kernel(
    const float* __restrict__ W, ushort* __restrict__ WT, int K, int ld, int coff)
{
  __shared__ float tile[32][33];
  const int tx = threadIdx.x, ty = threadIdx.y;
  const int k0 = blockIdx.x * 32, n0 = blockIdx.y * 32;
  #pragma unroll
  for (int i = 0; i < 4; ++i)
    tile[ty + i * 8][tx] = W[(size_t)(k0 + ty + i * 8) * ld + coff + n0 + tx];
  __syncthreads();
  #pragma unroll
  for (int i = 0; i < 4; ++i)
    WT[(size_t)(n0 + ty + i * 8) * K + k0 + tx] = f2bf(tile[tx][ty + i * 8]);
}

__global__ void cast_kernel(const float* __restrict__ X, ushort* __restrict__ Y, int n)
{
  int i = (blockIdx.x * 256 + threadIdx.x) * 4;
  if (i < n) {
    float4 v = *(const float4*)(X + i);
    ushort4 o;
    o.x = f2bf(v.x); o.y = f2bf(v.y); o.z = f2bf(v.z); o.w = f2bf(v.w);
    *(ushort4*)(Y + i) = o;
  }
}

// ---------------------------------------------------------------- host
static inline void gemm(hipStream_t st, const ushort* A, const ushort* BT,
                        const float* bias, const float* res, const ushort* aux,
                        float* outF, ushort* outB, int M, int N, int K)
{
  if (N == 640) {
    dim3 g((M + 127) / 128, N / 64);
    gemm_bf16_kernel<64><<<g, dim3(256), 0, st>>>(A, BT, bias, res, aux, outF, outB, M, N, K);
  } else {
    dim3 g((M + 127) / 128, N / 128);
    gemm_bf16_kernel<128><<<g, dim3(256), 0, st>>>(A, BT, bias, res, aux, outF, outB, M, N, K);
  }
}

extern "C" void kernel_launch(void* const* d_in, const int* in_sizes, int n_in,
                              void* d_out, int out_size, void* d_ws, size_t ws_size,
                              hipStream_t stream)
{
  const float* inputs  = (const float*)d_in[0];
  const float* context = (const float*)d_in[1];
  const float* gn_g    = (const float*)d_in[2];
  const float* gn_b    = (const float*)d_in[3];
  const float* w_proj1 = (const float*)d_in[4];
  const float* b_proj1 = (const float*)d_in[5];
  const float* ln1_g   = (const float*)d_in[6];
  const float* ln1_b   = (const float*)d_in[7];
  const float* wq1     = (const float*)d_in[8];
  const float* wk1     = (const float*)d_in[9];
  const float* wv1     = (const float*)d_in[10];
  const float* wo1     = (const float*)d_in[11];
  const float* bo1     = (const float*)d_in[12];
  const float* ln2_g   = (const float*)d_in[13];
  const float* ln2_b   = (const float*)d_in[14];
  const float* wq2     = (const float*)d_in[15];
  const float* wk2     = (const float*)d_in[16];
  const float* wv2     = (const float*)d_in[17];
  const float* wo2     = (const float*)d_in[18];
  const float* bo2     = (const float*)d_in[19];
  const float* ln3_g   = (const float*)d_in[20];
  const float* ln3_b   = (const float*)d_in[21];
  const float* w_geglu = (const float*)d_in[22];
  const float* b_geglu = (const float*)d_in[23];
  const float* w_ffout = (const float*)d_in[24];
  const float* b_ffout = (const float*)d_in[25];
  const float* w_proj2 = (const float*)d_in[26];
  const float* b_proj2 = (const float*)d_in[27];

  char* p = (char*)d_ws;
  auto alloc = [&](size_t bytes) -> char* {
    char* r = p; p += (bytes + 255) & ~(size_t)255; return r;
  };
  ushort* wT_p1   = (ushort*)alloc(640 * 640 * 2);
  ushort* wT_qkv1 = (ushort*)alloc((size_t)1920 * 640 * 2);
  ushort* wT_o1   = (ushort*)alloc(640 * 640 * 2);
  ushort* wT_q2   = (ushort*)alloc(640 * 640 * 2);
  ushort* wT_kv2  = (ushort*)alloc((size_t)1280 * 768 * 2);
  ushort* wT_o2   = (ushort*)alloc(640 * 640 * 2);
  ushort* wT_gx   = (ushort*)alloc((size_t)2560 * 640 * 2);
  ushort* wT_gg   = (ushort*)alloc((size_t)2560 * 640 * 2);
  ushort* wT_ff   = (ushort*)alloc((size_t)640 * 2560 * 2);
  ushort* wT_p2   = (ushort*)alloc(640 * 640 * 2);
  ushort* ctxb    = (ushort*)alloc((size_t)616 * 768 * 2);
  float*  x       = (float*)alloc((size_t)8192 * 640 * 4);
  ushort* lnb     = (ushort*)alloc((size_t)8192 * 640 * 2);
  ushort* R       = (ushort*)alloc((size_t)8192 * 2560 * 2);  // qkv / cross-q / hb
  ushort* gateb   = (ushort*)alloc((size_t)8192 * 2560 * 2);
  ushort* kvb     = (ushort*)alloc((size_t)616 * 1280 * 2);
  ushort* qkvb = R;      // self q/k/v [8192][1920]
  ushort* qbx  = R;      // cross q [8192][640]
  ushort* hb   = R;      // GEGLU out [8192][2560]
  ushort* ab   = lnb;    // attn out aliases lnb

  auto T = [&](const float* W, ushort* WT, int K, int Nout, int ld, int coff) {
    dim3 g(K / 32, Nout / 32);
    transpose_cast_kernel<<<g, dim3(32, 8), 0, stream>>>(W, WT, K, ld, coff);
  };
  T(w_proj1, wT_p1, 640, 640, 640, 0);
  T(wq1, wT_qkv1,              640, 640, 640, 0);
  T(wk1, wT_qkv1 + 640 * 640,  640, 640, 640, 0);
  T(wv1, wT_qkv1 + 1280 * 640, 640, 640, 640, 0);
  T(wo1, wT_o1, 640, 640, 640, 0);
  T(wq2, wT_q2, 640, 640, 640, 0);
  T(wk2, wT_kv2,             768, 640, 640, 0);
  T(wv2, wT_kv2 + 640 * 768, 768, 640, 640, 0);
  T(wo2, wT_o2, 640, 640, 640, 0);
  T(w_geglu, wT_gx, 640, 2560, 5120, 0);
  T(w_geglu, wT_gg, 640, 2560, 5120, 2560);
  T(w_ffout, wT_ff, 2560, 640, 640, 0);
  T(w_proj2, wT_p2, 640, 640, 640, 0);
  cast_kernel<<<dim3((616 * 768 / 4 + 255) / 256), dim3(256), 0, stream>>>(context, ctxb, 616 * 768);

  // GN -> proj1
  groupnorm_kernel<<<dim3(256), dim3(256), 0, stream>>>(inputs, gn_g, gn_b, lnb);
  gemm(stream, lnb, wT_p1, b_proj1, nullptr, nullptr, x, nullptr, 8192, 640, 640);

  // self-attention
  layernorm_kernel<<<dim3(2048), dim3(256), 0, stream>>>(x, ln1_g, ln1_b, lnb);
  gemm(stream, lnb, wT_qkv1, nullptr, nullptr, nullptr, nullptr, qkvb, 8192, 1920, 640);
  attn_mfma_kernel<<<dim3(1024), dim3(256), 0, stream>>>(qkvb, 1920, qkvb + 640, qkvb + 1280, 1920, ab, 1024, 1024);
  gemm(stream, ab, wT_o1, bo1, x, nullptr, x, nullptr, 8192, 640, 640);

  // cross-attention
  layernorm_kernel<<<dim3(2048), dim3(256), 0, stream>>>(x, ln2_g, ln2_b, lnb);
  gemm(stream, lnb, wT_q2, nullptr, nullptr, nullptr, nullptr, qbx, 8192, 640, 640);
  gemm(stream, ctxb, wT_kv2, nullptr, nullptr, nullptr, nullptr, kvb, 616, 1280, 768);
  attn_mfma_kernel<<<dim3(1024), dim3(256), 0, stream>>>(qbx, 640, kvb, kvb + 640, 1280, ab, 1024, 77);
  gemm(stream, ab, wT_o2, bo2, x, nullptr, x, nullptr, 8192, 640, 640);

  // GEGLU FF
  layernorm_kernel<<<dim3(2048), dim3(256), 0, stream>>>(x, ln3_g, ln3_b, lnb);
  gemm(stream, lnb, wT_gg, b_geglu + 2560, nullptr, nullptr, nullptr, gateb, 8192, 2560, 640);
  gemm(stream, lnb, wT_gx, b_geglu, nullptr, gateb, nullptr, hb, 8192, 2560, 640);
  gemm(stream, hb, wT_ff, b_ffout, x, nullptr, x, nullptr, 8192, 640, 2560);

  // proj2 + input residual
  cast_kernel<<<dim3((8192 * 640 / 4 + 255) / 256), dim3(256), 0, stream>>>(x, lnb, 8192 * 640);
  gemm(stream, lnb, wT_p2, b_proj2, inputs, nullptr, (float*)d_out, nullptr, 8192, 640, 640);
}